// Round 2
// baseline (815.724 us; speedup 1.0000x reference)
//
#include <hip/hip_runtime.h>
#include <math.h>

// B=16384 (M), C=4096 (N), D=256.
// logits[b,c] = -0.5*(sum_d (z-mu)^2*e^{-lv} + sum_d lv + D*log 2pi) - log C
// GEMM form (K=1536, f16 hi/lo split -> ~22-bit product precision):
//   A  = [z^2 , z]             (K=512, per row b)
//   W  = [-0.5*iv , mu*iv]     (K=512, per class c; -0.5 folded in)
//   quadterm = A_hi.W_hi + A_hi.W_lo + A_lo.W_hi   (drop lo*lo)
//   logits = GEMM(Atil, Wtil) + Kc[c]
//   Kc = -0.5*(sum mu^2 iv + sum lv) - 0.5*D*log(2pi) - log(C)

constexpr int M = 16384;
constexpr int N = 4096;
constexpr int K = 1536;
constexpr int BM = 128, BN = 128, BK = 64;

typedef _Float16 half_t;
typedef __attribute__((ext_vector_type(4))) _Float16 half4;
typedef __attribute__((ext_vector_type(8))) _Float16 half8;
typedef __attribute__((ext_vector_type(4))) float floatx4;

#define GLOBAL_AS(p) ((const __attribute__((address_space(1))) void*)(p))
#define LDS_AS(p) ((__attribute__((address_space(3))) void*)(p))

// wave-per-row: 4 rows/block, half4 (8B/lane) stores, no LDS/barriers.
__global__ __launch_bounds__(256) void prep_w_kernel(const float* __restrict__ mu,
                                                     const float* __restrict__ logvar,
                                                     half_t* __restrict__ Wt,
                                                     float* __restrict__ Kc) {
    const int tid = threadIdx.x;
    const int lane = tid & 63, wvi = tid >> 6;
    const int c = blockIdx.x * 4 + wvi;
    const float4 m4 = ((const float4*)mu)[(size_t)c * 64 + lane];
    const float4 l4 = ((const float4*)logvar)[(size_t)c * 64 + lane];
    const float mm[4] = {m4.x, m4.y, m4.z, m4.w};
    const float lv[4] = {l4.x, l4.y, l4.z, l4.w};
    half4 w1h, w1l, w2h, w2l;
    float s = 0.f;
    #pragma unroll
    for (int i = 0; i < 4; ++i) {
        const float iv = __expf(-lv[i]);
        const float w1 = -0.5f * iv;      // multiplies z^2
        const float w2 = mm[i] * iv;      // multiplies z
        w1h[i] = (half_t)w1; w1l[i] = (half_t)(w1 - (float)w1h[i]);
        w2h[i] = (half_t)w2; w2l[i] = (half_t)(w2 - (float)w2h[i]);
        s += mm[i] * mm[i] * iv + lv[i];
    }
    half4* row = (half4*)(Wt + (size_t)c * K);   // 384 half4 per row
    row[lane]       = w1h;   // pairs z2_hi
    row[64 + lane]  = w2h;   // pairs z_hi
    row[128 + lane] = w1l;   // pairs z2_hi
    row[192 + lane] = w2l;   // pairs z_hi
    row[256 + lane] = w1h;   // pairs z2_lo
    row[320 + lane] = w2h;   // pairs z_lo
    #pragma unroll
    for (int off = 1; off < 64; off <<= 1) s += __shfl_xor(s, off, 64);
    if (lane == 0)
        Kc[c] = -0.5f * s - 235.24826450039618f - 8.31776616671934f;
}

__global__ __launch_bounds__(256) void prep_a_kernel(const float* __restrict__ z,
                                                     half_t* __restrict__ At) {
    const int tid = threadIdx.x;
    const int lane = tid & 63, wvi = tid >> 6;
    const int b = blockIdx.x * 4 + wvi;
    const float4 z4 = ((const float4*)z)[(size_t)b * 64 + lane];
    const float zv[4] = {z4.x, z4.y, z4.z, z4.w};
    half4 z2h, z2l, zh, zl;
    #pragma unroll
    for (int i = 0; i < 4; ++i) {
        const float z2 = zv[i] * zv[i];
        z2h[i] = (half_t)z2; z2l[i] = (half_t)(z2 - (float)z2h[i]);
        zh[i]  = (half_t)zv[i]; zl[i] = (half_t)(zv[i] - (float)zh[i]);
    }
    half4* row = (half4*)(At + (size_t)b * K);
    row[lane]       = z2h;
    row[64 + lane]  = zh;
    row[128 + lane] = z2h;
    row[192 + lane] = zh;
    row[256 + lane] = z2l;
    row[320 + lane] = zl;
}

// m97-style GEMM: 128x128 tile, BK=64, 4 waves each computing 64x64 via 4x4
// frags of v_mfma_f32_16x16x32_f16. Staging via global_load_lds width=16.
// LDS rows are 64 f16 = 128 B; frag reads XOR-swizzle the 8 16B-chunks of
// each row by (row&7) so ds_read_b128 is bank-balanced; staging permutes the
// *global* source chunk instead (global_load_lds needs linear LDS dst).
// Epilogue: stage 64x128 f32 halves in LDS (reusing As/Bs), Kc fused, then
// fully-coalesced float4 global stores.
__global__ __launch_bounds__(256) void gemm_kernel(const half_t* __restrict__ At,
                                                   const half_t* __restrict__ Wt,
                                                   const float* __restrict__ Kc,
                                                   float* __restrict__ logits) {
    __shared__ char smem[BM * BK * 2 + BN * BK * 2];   // 32 KB
    half_t* As = (half_t*)smem;
    half_t* Bs = As + BM * BK;
    float*  Cs = (float*)smem;                          // 64 x 128 f32 (epilogue)

    const int bn0 = blockIdx.x * BN;
    const int bm0 = blockIdx.y * BM;
    const int tid = threadIdx.x;
    const int lane = tid & 63;
    const int wvi = tid >> 6;
    const int wm = (wvi & 1) * 64;
    const int wn = (wvi >> 1) * 64;
    const int quad = lane >> 4;
    const int l15 = lane & 15;

    // thread t, call i writes LDS bytes [t*16 + i*4096): row r=(t>>3)+i*32,
    // stored chunk s=t&7, logical chunk = s ^ (r&7)  (i*32 doesn't change r&7)
    const int r0 = tid >> 3;
    const int cl = ((tid & 7) ^ (r0 & 7)) * 8;   // element offset within row
    const char* gA = (const char*)(At + (size_t)(bm0 + r0) * K + cl);
    const char* gB = (const char*)(Wt + (size_t)(bn0 + r0) * K + cl);
    char* lA = (char*)As + tid * 16;
    char* lB = (char*)Bs + tid * 16;

    floatx4 acc[4][4] = {};

    for (int kt = 0; kt < K / BK; ++kt) {
        const size_t kb = (size_t)kt * BK * 2;  // byte offset along K
        #pragma unroll
        for (int i = 0; i < 4; ++i) {
            __builtin_amdgcn_global_load_lds(GLOBAL_AS(gA + kb + (size_t)i * 32 * K * 2),
                                             LDS_AS(lA + i * 4096), 16, 0, 0);
            __builtin_amdgcn_global_load_lds(GLOBAL_AS(gB + kb + (size_t)i * 32 * K * 2),
                                             LDS_AS(lB + i * 4096), 16, 0, 0);
        }
        __syncthreads();
        #pragma unroll
        for (int ks = 0; ks < 2; ++ks) {
            half8 af[4], bf[4];
            #pragma unroll
            for (int mi = 0; mi < 4; ++mi) {
                const int m = wm + mi * 16 + l15;
                const int c8 = (ks * 4 + quad) ^ (m & 7);
                af[mi] = *(const half8*)(As + m * BK + c8 * 8);
            }
            #pragma unroll
            for (int ni = 0; ni < 4; ++ni) {
                const int n = wn + ni * 16 + l15;
                const int c8 = (ks * 4 + quad) ^ (n & 7);
                bf[ni] = *(const half8*)(Bs + n * BK + c8 * 8);
            }
            #pragma unroll
            for (int mi = 0; mi < 4; ++mi)
                #pragma unroll
                for (int ni = 0; ni < 4; ++ni)
                    acc[mi][ni] = __builtin_amdgcn_mfma_f32_16x16x32_f16(
                        af[mi], bf[ni], acc[mi][ni], 0, 0, 0);
        }
        __syncthreads();
    }

    // epilogue: C/D layout col=lane&15, row=quad*4+reg (m89-verified).
    // Two halves of 64 rows x 128 cols staged in LDS, then float4 stores.
    float kc[4];
    #pragma unroll
    for (int ni = 0; ni < 4; ++ni) kc[ni] = Kc[bn0 + wn + ni * 16 + l15];

    const int seg = tid & 31;   // 16B column segment
    const int rg  = tid >> 5;   // 0..7 row group
    #pragma unroll
    for (int h = 0; h < 2; ++h) {
        __syncthreads();
        if ((wvi & 1) == h) {
            #pragma unroll
            for (int mi = 0; mi < 4; ++mi) {
                const int lr = mi * 16 + quad * 4;
                #pragma unroll
                for (int ni = 0; ni < 4; ++ni) {
                    const int lc = wn + ni * 16 + l15;
                    #pragma unroll
                    for (int r = 0; r < 4; ++r)
                        Cs[(lr + r) * 128 + lc] = acc[mi][ni][r] + kc[ni];
                }
            }
        }
        __syncthreads();
        #pragma unroll
        for (int i = 0; i < 8; ++i) {
            const int lr = i * 8 + rg;
            const float4 val = *(const float4*)(Cs + lr * 128 + seg * 4);
            *(float4*)(logits + (size_t)(bm0 + h * 64 + lr) * N + bn0 + seg * 4) = val;
        }
    }
}

// wave-per-row softmax+argmax: 4 rows/block, 16 float4/lane, butterfly
// shfl_xor reductions, no LDS, no barriers.
__global__ __launch_bounds__(256) void softmax_kernel(const float* __restrict__ logits,
                                                      float* __restrict__ probs,
                                                      float* __restrict__ pred) {
    const int tid = threadIdx.x;
    const int lane = tid & 63, wvi = tid >> 6;
    const int row = blockIdx.x * 4 + wvi;
    const float4* lrow = (const float4*)(logits + (size_t)row * N);
    float4 v[16];
    float vmax = -INFINITY;
    int vidx = 0;
    #pragma unroll
    for (int j = 0; j < 16; ++j) {
        v[j] = lrow[j * 64 + lane];
        const int base = (j * 64 + lane) * 4;
        if (v[j].x > vmax) { vmax = v[j].x; vidx = base; }
        if (v[j].y > vmax) { vmax = v[j].y; vidx = base + 1; }
        if (v[j].z > vmax) { vmax = v[j].z; vidx = base + 2; }
        if (v[j].w > vmax) { vmax = v[j].w; vidx = base + 3; }
    }
    #pragma unroll
    for (int off = 1; off < 64; off <<= 1) {
        const float ov = __shfl_xor(vmax, off, 64);
        const int oi = __shfl_xor(vidx, off, 64);
        if (ov > vmax || (ov == vmax && oi < vidx)) { vmax = ov; vidx = oi; }
    }
    float s = 0.f;
    #pragma unroll
    for (int j = 0; j < 16; ++j) {
        v[j].x = __expf(v[j].x - vmax);
        v[j].y = __expf(v[j].y - vmax);
        v[j].z = __expf(v[j].z - vmax);
        v[j].w = __expf(v[j].w - vmax);
        s += v[j].x + v[j].y + v[j].z + v[j].w;
    }
    #pragma unroll
    for (int off = 1; off < 64; off <<= 1) s += __shfl_xor(s, off, 64);
    const float inv = 1.f / s;
    float4* prow = (float4*)(probs + (size_t)row * N);
    #pragma unroll
    for (int j = 0; j < 16; ++j) {
        float4 o;
        o.x = v[j].x * inv; o.y = v[j].y * inv; o.z = v[j].z * inv; o.w = v[j].w * inv;
        prow[j * 64 + lane] = o;
    }
    if (lane == 0) pred[row] = (float)vidx;
}

extern "C" void kernel_launch(void* const* d_in, const int* in_sizes, int n_in,
                              void* d_out, int out_size, void* d_ws, size_t ws_size,
                              hipStream_t stream) {
    const float* z      = (const float*)d_in[0];
    const float* mu     = (const float*)d_in[1];
    const float* logvar = (const float*)d_in[2];
    float* out    = (float*)d_out;
    float* logits = out;                          // [M*N]
    float* probs  = out + (size_t)M * N;          // [M*N]
    float* pred   = out + (size_t)2 * M * N;      // [M]

    // Scratch (63 MB) carved from the probs region (268 MB): probs is written
    // only by the final softmax kernel, after the GEMM has consumed At/Wt/Kc.
    char* scratch = (char*)probs;
    half_t* At = (half_t*)scratch;                                          // M*K*2 = 50,331,648 B
    half_t* Wt = (half_t*)(scratch + (size_t)M * K * 2);                    // N*K*2 = 12,582,912 B
    float*  Kc = (float*)(scratch + (size_t)M * K * 2 + (size_t)N * K * 2); // 16 KB

    prep_w_kernel<<<N / 4, 256, 0, stream>>>(mu, logvar, Wt, Kc);
    prep_a_kernel<<<M / 4, 256, 0, stream>>>(z, At);
    gemm_kernel<<<dim3(N / BN, M / BM), 256, 0, stream>>>(At, Wt, Kc, logits);
    softmax_kernel<<<M / 4, 256, 0, stream>>>(logits, probs, pred);
}